// Round 4
// baseline (276.581 us; speedup 1.0000x reference)
//
#include <hip/hip_runtime.h>
#include <stdint.h>

#define BATCH 2
#define SEQ 2048
#define DMODEL 1024
#define NHEAD 16
#define HDIM 64
#define CVT_BLOCKS 15360

typedef __attribute__((ext_vector_type(8))) short bf16x8;
typedef __attribute__((ext_vector_type(4))) float f32x4;

__device__ __forceinline__ unsigned short f2bf(float f) {
  unsigned int u = __float_as_uint(f);
  u += 0x7fffu + ((u >> 16) & 1u);
  return (unsigned short)(u >> 16);
}
// pack 2 f32 -> 2 bf16 (round-to-nearest, ties-away): 2 adds + 1 v_perm
__device__ __forceinline__ unsigned int pk2bf(float a, float b) {
  return __builtin_amdgcn_perm(__float_as_uint(b) + 0x8000u,
                               __float_as_uint(a) + 0x8000u, 0x07060302u);
}
__device__ __forceinline__ void async_copy16(const void* g, void* l) {
  __builtin_amdgcn_global_load_lds(
      (const __attribute__((address_space(1))) void*)g,
      (__attribute__((address_space(3))) void*)l, 16, 0, 0);
}

// ---- fp32 -> bf16 for q,k,v,Wq,Wk,Wv; block CVT_BLOCKS computes mask lens ----
__global__ __launch_bounds__(256) void cvt_all(
    const float* __restrict__ q, const float* __restrict__ k,
    const float* __restrict__ v, const float* __restrict__ Wq,
    const float* __restrict__ Wk, const float* __restrict__ Wv,
    unsigned short* __restrict__ dst,
    const unsigned char* __restrict__ kp, const unsigned char* __restrict__ qp,
    int* __restrict__ lens) {
  if (blockIdx.x == CVT_BLOCKS) {  // mask lengths: klen->lens[0..1], qlen->lens[2..3]
    const int t = threadIdx.x, wave = t >> 6, lane = t & 63;
    const unsigned char* base = (wave < 2) ? kp : qp;
    const int b = wave & 1;
    const bool bytefmt = (base[1] != 0);  // element 1 always valid (len>=S/2)
    int cnt = 0;
    if (bytefmt) {
      const uint4* p = (const uint4*)(base + (size_t)b * SEQ);
#pragma unroll
      for (int g = 0; g < 2; g++) {
        const uint4 x = p[g * 64 + lane];
        const unsigned int w[4] = {x.x, x.y, x.z, x.w};
#pragma unroll
        for (int i = 0; i < 4; i++) {
          const unsigned int ww = w[i];
          cnt += ((ww & 0xffu) != 0) + ((ww & 0xff00u) != 0) +
                 ((ww & 0xff0000u) != 0) + ((ww & 0xff000000u) != 0);
        }
      }
    } else {
      const uint4* p = (const uint4*)(base + (size_t)b * SEQ * 4);
#pragma unroll
      for (int g = 0; g < 8; g++) {
        const uint4 x = p[g * 64 + lane];
        cnt += (x.x != 0) + (x.y != 0) + (x.z != 0) + (x.w != 0);
      }
    }
#pragma unroll
    for (int off = 32; off >= 1; off >>= 1) cnt += __shfl_xor(cnt, off, 64);
    if (lane == 0) lens[wave] = cnt;
    return;
  }
  const int g = blockIdx.x * 256 + threadIdx.x;
  const float* src;
  size_t off, dbase;
  if (g < 3 * (1 << 20)) {
    const int ti = g >> 20;
    src = (ti == 0) ? q : (ti == 1) ? k : v;
    off = (size_t)(g & ((1 << 20) - 1));
    dbase = (size_t)ti << 22;
  } else {
    const int gw = g - 3 * (1 << 20);
    const int ti = gw >> 18;
    src = (ti == 0) ? Wq : (ti == 1) ? Wk : Wv;
    off = (size_t)(gw & ((1 << 18) - 1));
    dbase = (3ull << 22) + ((size_t)ti << 20);
  }
  const float4 x = ((const float4*)src)[off];
  ushort4 o;
  o.x = f2bf(x.x); o.y = f2bf(x.y); o.z = f2bf(x.z); o.w = f2bf(x.w);
  *(ushort4*)(dst + dbase + off * 4) = o;
}

// ---- fused QKV projection; Q output pre-scaled by (1/sqrt(64))*log2(e) ----
__global__ __launch_bounds__(256) void qkv_proj(
    const unsigned short* __restrict__ xq, const unsigned short* __restrict__ xk,
    const unsigned short* __restrict__ xv,
    const unsigned short* __restrict__ Wq, const float* __restrict__ bq,
    const unsigned short* __restrict__ Wk, const float* __restrict__ bk,
    const unsigned short* __restrict__ Wv, const float* __restrict__ bv,
    unsigned short* __restrict__ Qo, unsigned short* __restrict__ Ko,
    unsigned short* __restrict__ Vo) {
  const int z = blockIdx.z;
  const unsigned short* x = (z == 0) ? xq : (z == 1) ? xk : xv;
  const unsigned short* W = (z == 0) ? Wq : (z == 1) ? Wk : Wv;
  const float* bias = (z == 0) ? bq : (z == 1) ? bk : bv;
  unsigned short* dst = (z == 0) ? Qo : (z == 1) ? Ko : Vo;
  const float osc = (z == 0) ? 0.18033688011112042f : 1.0f;

  __shared__ unsigned short As[128 * 32];
  __shared__ unsigned short Bs[128 * 32];

  const int t = threadIdx.x;
  const int wave = t >> 6, lane = t & 63, quad = lane >> 4, l16 = lane & 15;
  const int wm = wave >> 1, wn = wave & 1;
  const int m0 = blockIdx.y * 128, n0 = blockIdx.x * 128;

  const f32x4 fz = {0.f, 0.f, 0.f, 0.f};
  f32x4 acc[4][4];
#pragma unroll
  for (int i = 0; i < 4; i++)
#pragma unroll
    for (int j = 0; j < 4; j++) acc[i][j] = fz;

  for (int k0 = 0; k0 < DMODEL; k0 += 32) {
    __syncthreads();
#pragma unroll
    for (int c = 0; c < 2; c++) {
      const int g = c * 256 + t;
      const int row = g >> 2, cc = g & 3;
      async_copy16(x + (size_t)(m0 + row) * DMODEL + k0 + cc * 8,
                   (char*)As + (c * 256 + (t & 192)) * 16);
      async_copy16(W + (size_t)(n0 + row) * DMODEL + k0 + cc * 8,
                   (char*)Bs + (c * 256 + (t & 192)) * 16);
    }
    __syncthreads();
    bf16x8 af[4], bfr[4];
#pragma unroll
    for (int i = 0; i < 4; i++) {
      af[i] = *(const bf16x8*)(As + (wm * 64 + i * 16 + l16) * 32 + quad * 8);
      bfr[i] = *(const bf16x8*)(Bs + (wn * 64 + i * 16 + l16) * 32 + quad * 8);
    }
#pragma unroll
    for (int i = 0; i < 4; i++)
#pragma unroll
      for (int j = 0; j < 4; j++)
        acc[i][j] = __builtin_amdgcn_mfma_f32_16x16x32_bf16(af[i], bfr[j], acc[i][j], 0, 0, 0);
  }

#pragma unroll
  for (int j = 0; j < 4; j++) {
    const int n = n0 + wn * 64 + j * 16 + l16;
    const float bf_ = bias[n];
    const int h = n >> 6, hd = n & 63;
#pragma unroll
    for (int i = 0; i < 4; i++) {
#pragma unroll
      for (int r = 0; r < 4; r++) {
        const int m = m0 + wm * 64 + i * 16 + quad * 4 + r;
        const int bb = m >> 11, s = m & (SEQ - 1);
        dst[(((size_t)(bb * NHEAD + h) * SEQ + s) << 6) + hd] = f2bf((acc[i][j][r] + bf_) * osc);
      }
    }
  }
}

// ======================= attention v3 (unpaired, 4 blocks/CU) ================
// One 64-row q-tile per block. Swapped QK mfma(kf,qf) -> per-lane softmax
// (lane owns q=l16, 16 keys). XOR-swizzled LDS (phys 16B-group = logical^(row&7)).

__device__ __forceinline__ void stage_K(const unsigned short* __restrict__ Kp,
                                        int key0, unsigned short* dst, int t) {
#pragma unroll
  for (int c = 0; c < 2; c++) {
    const int slot = c * 256 + t;
    const int row = slot >> 3, pg = slot & 7;
    const int lg = pg ^ (row & 7);
    async_copy16(Kp + (size_t)(key0 + row) * HDIM + lg * 8,
                 (char*)dst + (c * 256 + (t & 192)) * 16);
  }
}

__device__ __forceinline__ void load_V(const unsigned short* __restrict__ Vp,
                                       int key0, int t, bf16x8& a, bf16x8& b) {
  a = *(const bf16x8*)(Vp + (size_t)(key0 + (t >> 3)) * HDIM + (t & 7) * 8);
  const int s1 = 256 + t;
  b = *(const bf16x8*)(Vp + (size_t)(key0 + (s1 >> 3)) * HDIM + (s1 & 7) * 8);
}

__device__ __forceinline__ void write_VT(unsigned short* vt, int t, bf16x8 a, bf16x8 b) {
#pragma unroll
  for (int c = 0; c < 2; c++) {
    const int slot = c * 256 + t;
    const int key = slot >> 3, u = slot & 7;
    const int K8 = key >> 3, k7 = key & 7;
    const bf16x8 vv = c ? b : a;
#pragma unroll
    for (int jj = 0; jj < 8; jj++) {  // staggered: ~2-way banks
      const int j = (jj + u) & 7;
      vt[(u * 8 + j) * 64 + ((K8 ^ j) * 8) + k7] = ((const unsigned short*)&vv)[j];
    }
  }
}

// Scores arrive pre-scaled (Q folded): p = exp2(s - m) directly.
template <bool MASKED>
__device__ __forceinline__ void softmax_update(
    const f32x4 s[4], int key0, int qrow, int klen, int quad, int l16,
    float& mst, float& lsum, f32x4 o[4], unsigned short* Pdst) {
  float pm[4][4];
  float rm = -__builtin_inff();
  if (MASKED) {
    const int kmax = ((qrow < klen - 1) ? qrow : klen - 1) - key0 - quad * 4;
#pragma unroll
    for (int nf = 0; nf < 4; nf++)
#pragma unroll
      for (int r = 0; r < 4; r++) {
        pm[nf][r] = (nf * 16 + r <= kmax) ? s[nf][r] : -__builtin_inff();
        rm = fmaxf(rm, pm[nf][r]);
      }
  } else {
#pragma unroll
    for (int nf = 0; nf < 4; nf++)
#pragma unroll
      for (int r = 0; r < 4; r++) {
        pm[nf][r] = s[nf][r];
        rm = fmaxf(rm, pm[nf][r]);
      }
  }
  rm = fmaxf(rm, __shfl_xor(rm, 16, 64));
  rm = fmaxf(rm, __shfl_xor(rm, 32, 64));
  const bool need = (__ballot(rm > mst) != 0ull);
  if (need) {
    const float mnew = fmaxf(mst, rm);
    const float alpha = exp2f(fmaxf(mst, -1e30f) - fmaxf(mnew, -1e30f));
    mst = mnew;
    lsum *= alpha;
    float ab[4];
#pragma unroll
    for (int r = 0; r < 4; r++) ab[r] = __shfl(alpha, quad * 4 + r, 64);
#pragma unroll
    for (int db = 0; db < 4; db++)
#pragma unroll
      for (int r = 0; r < 4; r++) o[db][r] *= ab[r];
  }
  const float mref = fmaxf(mst, -1e30f);
  float rs = 0.f;
#pragma unroll
  for (int nf = 0; nf < 4; nf++)
#pragma unroll
    for (int r = 0; r < 4; r++) {
      const float p = exp2f(pm[nf][r] - mref);
      pm[nf][r] = p;
      rs += p;
    }
  rs += __shfl_xor(rs, 16, 64);
  rs += __shfl_xor(rs, 32, 64);
  lsum += rs;
  const int sw = l16 & 7;
#pragma unroll
  for (int nf = 0; nf < 4; nf++) {
    uint2 w;
    w.x = pk2bf(pm[nf][0], pm[nf][1]);
    w.y = pk2bf(pm[nf][2], pm[nf][3]);
    const int grp = (nf * 2 + (quad >> 1)) ^ sw;
    *(uint2*)(Pdst + l16 * 64 + grp * 8 + (quad & 1) * 4) = w;
  }
}

__global__ __launch_bounds__(256, 4) void attn_kernel(
    const unsigned short* __restrict__ Qb, const unsigned short* __restrict__ Kb,
    const unsigned short* __restrict__ Vb, const float* __restrict__ qin,
    const int* __restrict__ lens, float* __restrict__ out) {
  const int qi = 31 - blockIdx.x, h = blockIdx.y, b = blockIdx.z;
  const int bh = b * NHEAD + h;
  const int t = threadIdx.x, wave = t >> 6, lane = t & 63, quad = lane >> 4, l16 = lane & 15;
  const int sw = l16 & 7;
  const int klen = lens[b], qlen = lens[2 + b];

  if (qi * 64 >= qlen) {  // fully padded q-tile: out = residual only
    const int row = qi * 64 + (t >> 2);
    const size_t base = (size_t)(b * SEQ + row) * DMODEL + h * HDIM;
    const float4* src = (const float4*)(qin + base);
    float4* dst = (float4*)(out + base);
#pragma unroll
    for (int c = 0; c < 4; c++) dst[(t & 3) * 4 + c] = src[(t & 3) * 4 + c];
    return;
  }

  __shared__ unsigned short Ks[2][64 * 64];
  __shared__ unsigned short VT[2][64 * 64];
  __shared__ unsigned short Ps[4][16 * 64];

  const unsigned short* Qp = Qb + (size_t)bh * SEQ * HDIM;
  const unsigned short* Kp = Kb + (size_t)bh * SEQ * HDIM;
  const unsigned short* Vp = Vb + (size_t)bh * SEQ * HDIM;

  const int qrow = qi * 64 + wave * 16 + l16;
  const bf16x8 qf0 = *(const bf16x8*)(Qp + (size_t)qrow * HDIM + quad * 8);
  const bf16x8 qf1 = *(const bf16x8*)(Qp + (size_t)qrow * HDIM + 32 + quad * 8);

  const f32x4 fz = {0.f, 0.f, 0.f, 0.f};
  f32x4 o[4];
#pragma unroll
  for (int i = 0; i < 4; i++) o[i] = fz;
  float mst = -__builtin_inff(), lsum = 0.f;

  const int klt = (klen + 63) >> 6;
  const int ktot = (qi + 1 < klt) ? qi + 1 : klt;

  stage_K(Kp, 0, Ks[0], t);
  bf16x8 va, vb2;
  load_V(Vp, 0, t, va, vb2);
  write_VT(VT[0], t, va, vb2);

  for (int kt = 0; kt < ktot; kt++) {
    const int cb = kt & 1, nb = cb ^ 1;
    const int key0 = kt * 64;
    __syncthreads();  // K[cb] arrived, VT[cb] written, buffers[nb] free
    if (kt + 1 < ktot) {
      stage_K(Kp, key0 + 64, Ks[nb], t);
      load_V(Vp, key0 + 64, t, va, vb2);
    }
    const unsigned short* ks = Ks[cb];
    const unsigned short* vt = VT[cb];

    f32x4 s[4];
#pragma unroll
    for (int nf = 0; nf < 4; nf++) {
      const bf16x8 kf0 = *(const bf16x8*)(ks + (nf * 16 + l16) * 64 + (quad ^ sw) * 8);
      const bf16x8 kf1 = *(const bf16x8*)(ks + (nf * 16 + l16) * 64 + ((quad + 4) ^ sw) * 8);
      f32x4 a = fz;
      a = __builtin_amdgcn_mfma_f32_16x16x32_bf16(kf0, qf0, a, 0, 0, 0);
      a = __builtin_amdgcn_mfma_f32_16x16x32_bf16(kf1, qf1, a, 0, 0, 0);
      s[nf] = a;
    }

    const bool nomask = (kt < qi) && (key0 + 63 < klen);
    if (nomask)
      softmax_update<false>(s, key0, qrow, klen, quad, l16, mst, lsum, o, Ps[wave]);
    else
      softmax_update<true>(s, key0, qrow, klen, quad, l16, mst, lsum, o, Ps[wave]);

    const bf16x8 pf0 = *(const bf16x8*)(Ps[wave] + l16 * 64 + (quad ^ sw) * 8);
    const bf16x8 pf1 = *(const bf16x8*)(Ps[wave] + l16 * 64 + ((quad + 4) ^ sw) * 8);
#pragma unroll
    for (int db = 0; db < 4; db++) {
      const bf16x8 vt0 = *(const bf16x8*)(vt + (db * 16 + l16) * 64 + (quad ^ sw) * 8);
      const bf16x8 vt1 = *(const bf16x8*)(vt + (db * 16 + l16) * 64 + ((quad + 4) ^ sw) * 8);
      o[db] = __builtin_amdgcn_mfma_f32_16x16x32_bf16(pf0, vt0, o[db], 0, 0, 0);
      o[db] = __builtin_amdgcn_mfma_f32_16x16x32_bf16(pf1, vt1, o[db], 0, 0, 0);
    }
    if (kt + 1 < ktot) write_VT(VT[nb], t, va, vb2);
  }

  const float invv = (lsum > 0.f) ? 1.f / lsum : 0.f;
  float ib[4];
#pragma unroll
  for (int r = 0; r < 4; r++) ib[r] = __shfl(invv, quad * 4 + r, 64);
#pragma unroll
  for (int db = 0; db < 4; db++) {
    const int col = h * HDIM + db * 16 + l16;
#pragma unroll
    for (int r = 0; r < 4; r++) {
      const int i = qi * 64 + wave * 16 + quad * 4 + r;
      const size_t idx = (size_t)(b * SEQ + i) * DMODEL + col;
      out[idx] = ((i < qlen) ? o[db][r] * ib[r] : 0.f) + qin[idx];
    }
  }
}

extern "C" void kernel_launch(void* const* d_in, const int* in_sizes, int n_in,
                              void* d_out, int out_size, void* d_ws, size_t ws_size,
                              hipStream_t stream) {
  (void)in_sizes; (void)n_in; (void)out_size; (void)ws_size;
  const float* q = (const float*)d_in[0];
  const float* k = (const float*)d_in[1];
  const float* v = (const float*)d_in[2];
  const float* Wq = (const float*)d_in[3];
  const float* bq = (const float*)d_in[4];
  const float* Wk = (const float*)d_in[5];
  const float* bk = (const float*)d_in[6];
  const float* Wv = (const float*)d_in[7];
  const float* bv = (const float*)d_in[8];
  const unsigned char* kpm = (const unsigned char*)d_in[9];
  const unsigned char* qpm = (const unsigned char*)d_in[10];
  float* out = (float*)d_out;

  const size_t tsz = (size_t)BATCH * SEQ * DMODEL;  // 4 Mi
  const size_t wsz = (size_t)DMODEL * DMODEL;       // 1 Mi

  char* ws = (char*)d_ws;
  int* lens = (int*)ws;
  unsigned short* cvt_base = (unsigned short*)(ws + 256);
  unsigned short* qb16 = cvt_base;
  unsigned short* kb16 = qb16 + tsz;
  unsigned short* vb16 = kb16 + tsz;
  unsigned short* Wqb = vb16 + tsz;
  unsigned short* Wkb = Wqb + wsz;
  unsigned short* Wvb = Wkb + wsz;
  unsigned short* Qw = Wvb + wsz;
  unsigned short* Kw = Qw + tsz;
  unsigned short* Vw = Kw + tsz;

  cvt_all<<<dim3(CVT_BLOCKS + 1), dim3(256), 0, stream>>>(q, k, v, Wq, Wk, Wv,
                                                          cvt_base, kpm, qpm, lens);
  qkv_proj<<<dim3(8, 32, 3), dim3(256), 0, stream>>>(qb16, kb16, vb16, Wqb, bq, Wkb, bk, Wvb, bv, Qw, Kw, Vw);
  attn_kernel<<<dim3(32, NHEAD, BATCH), dim3(256), 0, stream>>>(Qw, Kw, Vw, q, lens, out);
}

// Round 5
// 251.017 us; speedup vs baseline: 1.1018x; 1.1018x over previous
//
#include <hip/hip_runtime.h>
#include <stdint.h>

#define BATCH 2
#define SEQ 2048
#define DMODEL 1024
#define NHEAD 16
#define HDIM 64
#define CVT_BLOCKS 15360

typedef __attribute__((ext_vector_type(8))) short bf16x8;
typedef __attribute__((ext_vector_type(4))) float f32x4;

__device__ __forceinline__ unsigned short f2bf(float f) {
  unsigned int u = __float_as_uint(f);
  u += 0x7fffu + ((u >> 16) & 1u);
  return (unsigned short)(u >> 16);
}
// pack 2 f32 -> 2 bf16 (round-to-nearest-ties-away): 2 adds + 1 v_perm
__device__ __forceinline__ unsigned int pk2bf(float a, float b) {
  return __builtin_amdgcn_perm(__float_as_uint(b) + 0x8000u,
                               __float_as_uint(a) + 0x8000u, 0x07060302u);
}
__device__ __forceinline__ void async_copy16(const void* g, void* l) {
  __builtin_amdgcn_global_load_lds(
      (const __attribute__((address_space(1))) void*)g,
      (__attribute__((address_space(3))) void*)l, 16, 0, 0);
}

// ---- fp32 -> bf16 for q,k,v,Wq,Wk,Wv; block CVT_BLOCKS computes mask lens ----
__global__ __launch_bounds__(256) void cvt_all(
    const float* __restrict__ q, const float* __restrict__ k,
    const float* __restrict__ v, const float* __restrict__ Wq,
    const float* __restrict__ Wk, const float* __restrict__ Wv,
    unsigned short* __restrict__ dst,
    const unsigned char* __restrict__ kp, const unsigned char* __restrict__ qp,
    int* __restrict__ lens) {
  if (blockIdx.x == CVT_BLOCKS) {  // klen->lens[0..1], qlen->lens[2..3]
    const int t = threadIdx.x, wave = t >> 6, lane = t & 63;
    const unsigned char* base = (wave < 2) ? kp : qp;
    const int b = wave & 1;
    const bool bytefmt = (base[1] != 0);  // element 1 always valid (len>=S/2)
    int cnt = 0;
    if (bytefmt) {
      const uint4* p = (const uint4*)(base + (size_t)b * SEQ);
#pragma unroll
      for (int g = 0; g < 2; g++) {
        const uint4 x = p[g * 64 + lane];
        const unsigned int w[4] = {x.x, x.y, x.z, x.w};
#pragma unroll
        for (int i = 0; i < 4; i++) {
          const unsigned int ww = w[i];
          cnt += ((ww & 0xffu) != 0) + ((ww & 0xff00u) != 0) +
                 ((ww & 0xff0000u) != 0) + ((ww & 0xff000000u) != 0);
        }
      }
    } else {
      const uint4* p = (const uint4*)(base + (size_t)b * SEQ * 4);
#pragma unroll
      for (int g = 0; g < 8; g++) {
        const uint4 x = p[g * 64 + lane];
        cnt += (x.x != 0) + (x.y != 0) + (x.z != 0) + (x.w != 0);
      }
    }
#pragma unroll
    for (int off = 32; off >= 1; off >>= 1) cnt += __shfl_xor(cnt, off, 64);
    if (lane == 0) lens[wave] = cnt;
    return;
  }
  const int g = blockIdx.x * 256 + threadIdx.x;
  const float* src;
  size_t off, dbase;
  if (g < 3 * (1 << 20)) {
    const int ti = g >> 20;
    src = (ti == 0) ? q : (ti == 1) ? k : v;
    off = (size_t)(g & ((1 << 20) - 1));
    dbase = (size_t)ti << 22;
  } else {
    const int gw = g - 3 * (1 << 20);
    const int ti = gw >> 18;
    src = (ti == 0) ? Wq : (ti == 1) ? Wk : Wv;
    off = (size_t)(gw & ((1 << 18) - 1));
    dbase = (3ull << 22) + ((size_t)ti << 20);
  }
  const float4 x = ((const float4*)src)[off];
  ushort4 o;
  o.x = f2bf(x.x); o.y = f2bf(x.y); o.z = f2bf(x.z); o.w = f2bf(x.w);
  *(ushort4*)(dst + dbase + off * 4) = o;
}

// ---- fused QKV projection; Q output pre-scaled by (1/sqrt(64))*log2(e) ----
__global__ __launch_bounds__(256) void qkv_proj(
    const unsigned short* __restrict__ xq, const unsigned short* __restrict__ xk,
    const unsigned short* __restrict__ xv,
    const unsigned short* __restrict__ Wq, const float* __restrict__ bq,
    const unsigned short* __restrict__ Wk, const float* __restrict__ bk,
    const unsigned short* __restrict__ Wv, const float* __restrict__ bv,
    unsigned short* __restrict__ Qo, unsigned short* __restrict__ Ko,
    unsigned short* __restrict__ Vo) {
  const int z = blockIdx.z;
  const unsigned short* x = (z == 0) ? xq : (z == 1) ? xk : xv;
  const unsigned short* W = (z == 0) ? Wq : (z == 1) ? Wk : Wv;
  const float* bias = (z == 0) ? bq : (z == 1) ? bk : bv;
  unsigned short* dst = (z == 0) ? Qo : (z == 1) ? Ko : Vo;
  const float osc = (z == 0) ? 0.18033688011112042f : 1.0f;

  __shared__ unsigned short As[128 * 32];
  __shared__ unsigned short Bs[128 * 32];

  const int t = threadIdx.x;
  const int wave = t >> 6, lane = t & 63, quad = lane >> 4, l16 = lane & 15;
  const int wm = wave >> 1, wn = wave & 1;
  const int m0 = blockIdx.y * 128, n0 = blockIdx.x * 128;

  const f32x4 fz = {0.f, 0.f, 0.f, 0.f};
  f32x4 acc[4][4];
#pragma unroll
  for (int i = 0; i < 4; i++)
#pragma unroll
    for (int j = 0; j < 4; j++) acc[i][j] = fz;

  for (int k0 = 0; k0 < DMODEL; k0 += 32) {
    __syncthreads();
#pragma unroll
    for (int c = 0; c < 2; c++) {
      const int g = c * 256 + t;
      const int row = g >> 2, cc = g & 3;
      async_copy16(x + (size_t)(m0 + row) * DMODEL + k0 + cc * 8,
                   (char*)As + (c * 256 + (t & 192)) * 16);
      async_copy16(W + (size_t)(n0 + row) * DMODEL + k0 + cc * 8,
                   (char*)Bs + (c * 256 + (t & 192)) * 16);
    }
    __syncthreads();
    bf16x8 af[4], bfr[4];
#pragma unroll
    for (int i = 0; i < 4; i++) {
      af[i] = *(const bf16x8*)(As + (wm * 64 + i * 16 + l16) * 32 + quad * 8);
      bfr[i] = *(const bf16x8*)(Bs + (wn * 64 + i * 16 + l16) * 32 + quad * 8);
    }
#pragma unroll
    for (int i = 0; i < 4; i++)
#pragma unroll
      for (int j = 0; j < 4; j++)
        acc[i][j] = __builtin_amdgcn_mfma_f32_16x16x32_bf16(af[i], bfr[j], acc[i][j], 0, 0, 0);
  }

#pragma unroll
  for (int j = 0; j < 4; j++) {
    const int n = n0 + wn * 64 + j * 16 + l16;
    const float bf_ = bias[n];
    const int h = n >> 6, hd = n & 63;
#pragma unroll
    for (int i = 0; i < 4; i++) {
#pragma unroll
      for (int r = 0; r < 4; r++) {
        const int m = m0 + wm * 64 + i * 16 + quad * 4 + r;
        const int bb = m >> 11, s = m & (SEQ - 1);
        dst[(((size_t)(bb * NHEAD + h) * SEQ + s) << 6) + hd] = f2bf((acc[i][j][r] + bf_) * osc);
      }
    }
  }
}

// ============ attention v4: 128-key chunks, single-buffer, LPT queue ========
// 1024 blocks (one 64-row q-tile each), longest-first; 48KB LDS -> 3 blocks/CU
// (768 resident + 256 queued = backfill balance). Swapped QK mfma(kf,qf):
// lane owns q=l16. XOR-swizzled LDS throughout.

// Scores arrive pre-scaled (Q folded): p = exp2(s - m) directly.
template <bool MASKED>
__device__ __forceinline__ void softmax_update(
    const f32x4 s[8], int key0, int qrow, int klen, int quad, int l16,
    float& mst, float& lsum, f32x4 o[4], unsigned short* Pdst) {
  float pm[8][4];
  float rm = -__builtin_inff();
  if (MASKED) {
    const int kmax = ((qrow < klen - 1) ? qrow : klen - 1) - key0 - quad * 4;
#pragma unroll
    for (int nf = 0; nf < 8; nf++)
#pragma unroll
      for (int r = 0; r < 4; r++) {
        pm[nf][r] = (nf * 16 + r <= kmax) ? s[nf][r] : -__builtin_inff();
        rm = fmaxf(rm, pm[nf][r]);
      }
  } else {
#pragma unroll
    for (int nf = 0; nf < 8; nf++)
#pragma unroll
      for (int r = 0; r < 4; r++) {
        pm[nf][r] = s[nf][r];
        rm = fmaxf(rm, pm[nf][r]);
      }
  }
  rm = fmaxf(rm, __shfl_xor(rm, 16, 64));
  rm = fmaxf(rm, __shfl_xor(rm, 32, 64));
  if (__ballot(rm > mst) != 0ull) {
    const float mnew = fmaxf(mst, rm);
    const float alpha = exp2f(fmaxf(mst, -1e30f) - fmaxf(mnew, -1e30f));
    mst = mnew;
    lsum *= alpha;
    float ab[4];
#pragma unroll
    for (int r = 0; r < 4; r++) ab[r] = __shfl(alpha, quad * 4 + r, 64);
#pragma unroll
    for (int db = 0; db < 4; db++)
#pragma unroll
      for (int r = 0; r < 4; r++) o[db][r] *= ab[r];
  }
  const float mref = fmaxf(mst, -1e30f);
  float rs = 0.f;
#pragma unroll
  for (int nf = 0; nf < 8; nf++)
#pragma unroll
    for (int r = 0; r < 4; r++) {
      const float p = exp2f(pm[nf][r] - mref);
      pm[nf][r] = p;
      rs += p;
    }
  rs += __shfl_xor(rs, 16, 64);
  rs += __shfl_xor(rs, 32, 64);
  lsum += rs;
  // P row = q = l16 (128 keys, stride 128); phys 8-short group = logical^l16
#pragma unroll
  for (int nf = 0; nf < 8; nf++) {
    uint2 w;
    w.x = pk2bf(pm[nf][0], pm[nf][1]);
    w.y = pk2bf(pm[nf][2], pm[nf][3]);
    const int grp = (nf * 2 + (quad >> 1)) ^ l16;
    *(uint2*)(Pdst + l16 * 128 + grp * 8 + (quad & 1) * 4) = w;
  }
}

__global__ __launch_bounds__(256, 2) void attn_kernel(
    const unsigned short* __restrict__ Qb, const unsigned short* __restrict__ Kb,
    const unsigned short* __restrict__ Vb, const float* __restrict__ qin,
    const int* __restrict__ lens, float* __restrict__ out) {
  const int qi = 31 - blockIdx.x, h = blockIdx.y, b = blockIdx.z;
  const int bh = b * NHEAD + h;
  const int t = threadIdx.x, wave = t >> 6, lane = t & 63, quad = lane >> 4, l16 = lane & 15;
  const int klen = lens[b], qlen = lens[2 + b];

  if (qi * 64 >= qlen) {  // fully padded q-tile: out = residual only
    const int row = qi * 64 + (t >> 2);
    const size_t base = (size_t)(b * SEQ + row) * DMODEL + h * HDIM;
    const float4* src = (const float4*)(qin + base);
    float4* dst = (float4*)(out + base);
#pragma unroll
    for (int c = 0; c < 4; c++) dst[(t & 3) * 4 + c] = src[(t & 3) * 4 + c];
    return;
  }

  __shared__ unsigned short Ks[128 * 64];     // [key][d], xor-swizzle row&7
  __shared__ unsigned short VT[64 * 128];     // [d][key], xor-swizzle d&15
  __shared__ unsigned short Ps[4][16 * 128];  // per-wave P [q=16][key=128]

  const unsigned short* Qp = Qb + (size_t)bh * SEQ * HDIM;
  const unsigned short* Kp = Kb + (size_t)bh * SEQ * HDIM;
  const unsigned short* Vp = Vb + (size_t)bh * SEQ * HDIM;

  const int qrow = qi * 64 + wave * 16 + l16;
  const bf16x8 qf0 = *(const bf16x8*)(Qp + (size_t)qrow * HDIM + quad * 8);
  const bf16x8 qf1 = *(const bf16x8*)(Qp + (size_t)qrow * HDIM + 32 + quad * 8);

  const f32x4 fz = {0.f, 0.f, 0.f, 0.f};
  f32x4 o[4];
#pragma unroll
  for (int i = 0; i < 4; i++) o[i] = fz;
  float mst = -__builtin_inff(), lsum = 0.f;

  const int kend = ((qi * 64 + 64) < klen) ? (qi * 64 + 64) : klen;
  const int ktot = (kend + 127) >> 7;

  for (int kt = 0; kt < ktot; kt++) {
    const int key0 = kt << 7;
    __syncthreads();  // all waves done reading previous chunk's LDS
    // stage K: 128 rows x 64 d (4 x async16/thread)
#pragma unroll
    for (int c = 0; c < 4; c++) {
      const int slot = c * 256 + t;
      const int row = slot >> 3, pg = slot & 7;
      async_copy16(Kp + (size_t)(key0 + row) * HDIM + (pg ^ (row & 7)) * 8,
                   (char*)Ks + (c * 256 + (t & 192)) * 16);
    }
    // V -> registers -> transposed LDS (short-lived regs)
#pragma unroll
    for (int c = 0; c < 4; c++) {
      const int slot = c * 256 + t;
      const int key = slot >> 3, u = slot & 7, d8 = u * 8;
      const bf16x8 vv = *(const bf16x8*)(Vp + (size_t)(key0 + key) * HDIM + d8);
      const int K16 = key >> 3, k7 = key & 7;
#pragma unroll
      for (int jj = 0; jj < 8; jj++) {  // staggered banks
        const int j = (jj + u) & 7;
        const int d = d8 + j;
        VT[d * 128 + ((K16 ^ (d & 15)) * 8) + k7] = ((const unsigned short*)&vv)[j];
      }
    }
    __syncthreads();  // K arrived (vmcnt drain), VT written

    f32x4 s[8];
#pragma unroll
    for (int nf = 0; nf < 8; nf++) {
      const int row = nf * 16 + l16;
      const int sw = row & 7;
      const bf16x8 kf0 = *(const bf16x8*)(Ks + row * 64 + (quad ^ sw) * 8);
      const bf16x8 kf1 = *(const bf16x8*)(Ks + row * 64 + ((quad + 4) ^ sw) * 8);
      f32x4 a = fz;
      a = __builtin_amdgcn_mfma_f32_16x16x32_bf16(kf0, qf0, a, 0, 0, 0);
      a = __builtin_amdgcn_mfma_f32_16x16x32_bf16(kf1, qf1, a, 0, 0, 0);
      s[nf] = a;
    }

    const bool nomask = (key0 + 127 <= qi * 64) && (key0 + 127 < klen);
    if (nomask)
      softmax_update<false>(s, key0, qrow, klen, quad, l16, mst, lsum, o, Ps[wave]);
    else
      softmax_update<true>(s, key0, qrow, klen, quad, l16, mst, lsum, o, Ps[wave]);

    // PV: 4 k-steps of 32 keys; A-frag keys = ks*32+quad*8+j
    bf16x8 pf[4];
#pragma unroll
    for (int ks = 0; ks < 4; ks++)
      pf[ks] = *(const bf16x8*)(Ps[wave] + l16 * 128 + ((ks * 4 + quad) ^ l16) * 8);
#pragma unroll
    for (int db = 0; db < 4; db++) {
      const int d = db * 16 + l16;
#pragma unroll
      for (int ks = 0; ks < 4; ks++) {
        const bf16x8 vt = *(const bf16x8*)(VT + d * 128 + ((ks * 4 + quad) ^ l16) * 8);
        o[db] = __builtin_amdgcn_mfma_f32_16x16x32_bf16(pf[ks], vt, o[db], 0, 0, 0);
      }
    }
  }

  const float invv = (lsum > 0.f) ? 1.f / lsum : 0.f;
  float ib[4];
#pragma unroll
  for (int r = 0; r < 4; r++) ib[r] = __shfl(invv, quad * 4 + r, 64);
#pragma unroll
  for (int db = 0; db < 4; db++) {
    const int col = h * HDIM + db * 16 + l16;
#pragma unroll
    for (int r = 0; r < 4; r++) {
      const int i = qi * 64 + wave * 16 + quad * 4 + r;
      const size_t idx = (size_t)(b * SEQ + i) * DMODEL + col;
      out[idx] = ((i < qlen) ? o[db][r] * ib[r] : 0.f) + qin[idx];
    }
  }
}

extern "C" void kernel_launch(void* const* d_in, const int* in_sizes, int n_in,
                              void* d_out, int out_size, void* d_ws, size_t ws_size,
                              hipStream_t stream) {
  (void)in_sizes; (void)n_in; (void)out_size; (void)ws_size;
  const float* q = (const float*)d_in[0];
  const float* k = (const float*)d_in[1];
  const float* v = (const float*)d_in[2];
  const float* Wq = (const float*)d_in[3];
  const float* bq = (const float*)d_in[4];
  const float* Wk = (const float*)d_in[5];
  const float* bk = (const float*)d_in[6];
  const float* Wv = (const float*)d_in[7];
  const float* bv = (const float*)d_in[8];
  const unsigned char* kpm = (const unsigned char*)d_in[9];
  const unsigned char* qpm = (const unsigned char*)d_in[10];
  float* out = (float*)d_out;

  const size_t tsz = (size_t)BATCH * SEQ * DMODEL;  // 4 Mi
  const size_t wsz = (size_t)DMODEL * DMODEL;       // 1 Mi

  char* ws = (char*)d_ws;
  int* lens = (int*)ws;
  unsigned short* cvt_base = (unsigned short*)(ws + 256);
  unsigned short* qb16 = cvt_base;
  unsigned short* kb16 = qb16 + tsz;
  unsigned short* vb16 = kb16 + tsz;
  unsigned short* Wqb = vb16 + tsz;
  unsigned short* Wkb = Wqb + wsz;
  unsigned short* Wvb = Wkb + wsz;
  unsigned short* Qw = Wvb + wsz;
  unsigned short* Kw = Qw + tsz;
  unsigned short* Vw = Kw + tsz;

  cvt_all<<<dim3(CVT_BLOCKS + 1), dim3(256), 0, stream>>>(q, k, v, Wq, Wk, Wv,
                                                          cvt_base, kpm, qpm, lens);
  qkv_proj<<<dim3(8, 32, 3), dim3(256), 0, stream>>>(qb16, kb16, vb16, Wqb, bq, Wkb, bk, Wvb, bv, Qw, Kw, Vw);
  attn_kernel<<<dim3(32, NHEAD, BATCH), dim3(256), 0, stream>>>(Qw, Kw, Vw, q, lens, out);
}